// Round 1
// baseline (117.811 us; speedup 1.0000x reference)
//
#include <hip/hip_runtime.h>
#include <hip/hip_bf16.h>
#include <float.h>

#define B_ 64
#define C_ 512
#define Q_ 64
#define D_ 256
#define CT 16   // context rows per block in main kernel

typedef _Float16 h2_t __attribute__((ext_vector_type(2)));

union U32H2 { uint32_t u; h2_t h; };

__device__ __forceinline__ uint32_t pack_h2(float a, float b) {
  U32H2 v; v.h = h2_t{(_Float16)a, (_Float16)b}; return v.u;
}
__device__ __forceinline__ h2_t as_h2(uint32_t u) { U32H2 v; v.u = u; return v.h; }

__device__ __forceinline__ float dot2acc(uint32_t q, uint32_t c, float acc) {
#if __has_builtin(__builtin_amdgcn_fdot2)
  return __builtin_amdgcn_fdot2(as_h2(q), as_h2(c), acc, false);
#else
  h2_t ha = as_h2(q), hb = as_h2(c);
  return acc + (float)ha.x * (float)hb.x + (float)ha.y * (float)hb.y;
#endif
}
__device__ __forceinline__ float2 h2f2(uint32_t u) {
  h2_t h = as_h2(u);
  float2 r; r.x = (float)h.x; r.y = (float)h.y; return r;
}

__device__ __forceinline__ float wred_sum(float v) {
#pragma unroll
  for (int off = 32; off > 0; off >>= 1) v += __shfl_xor(v, off, 64);
  return v;
}
__device__ __forceinline__ float wred_max(float v) {
#pragma unroll
  for (int off = 32; off > 0; off >>= 1) v = fmaxf(v, __shfl_xor(v, off, 64));
  return v;
}

// K1: out[row] = dot(src[row, 0:256], wgt[0:256])
__global__ __launch_bounds__(256) void k_rowdot(const float* __restrict__ src,
                                                const float* __restrict__ wgt,
                                                float* __restrict__ out, int nrows) {
  int wv = threadIdx.x >> 6, ln = threadIdx.x & 63;
  int row = blockIdx.x * 4 + wv;
  if (row >= nrows) return;
  float4 s4 = *(const float4*)(src + (size_t)row * D_ + 4 * ln);
  float4 w4 = *(const float4*)(wgt + 4 * ln);
  float p = s4.x * w4.x + s4.y * w4.y + s4.z * w4.z + s4.w * w4.w;
  p = wred_sum(p);
  if (ln == 0) out[row] = p;
}

// K2: per (b, 16-row c-tile): sim -> softmax_q -> c2q; writes g[0:3D], simmax
__global__ __launch_bounds__(256) void k_main(
    const float* __restrict__ ctx, const float* __restrict__ qst,
    const int* __restrict__ qmask, const float* __restrict__ w,
    const float* __restrict__ qwq_g, float* __restrict__ g,
    float* __restrict__ simmax_g) {
  // question[b] as f16 pairs, 16B-chunk XOR-swizzled per row (row=lane reads in sim loop)
  __shared__ __align__(16) uint32_t qldf[Q_ * 128];
  __shared__ __align__(16) uint32_t cmld[CT][132];  // ctx*w_m, f16 pairs (uniform reads)
  __shared__ __align__(16) uint32_t crld[CT][132];  // raw ctx, f16 pairs (for cwc)
  __shared__ float ald[CT][65];
  __shared__ float qwq_l[Q_];
  __shared__ int qml[Q_];
  __shared__ uint32_t wcp[128];

  const int b = blockIdx.y;
  const int c0 = blockIdx.x * CT;
  const int t = threadIdx.x;

  // ---- stage question[b] (swizzled) ----
  const float* qb = qst + (size_t)b * Q_ * D_;
  for (int idx = t; idx < Q_ * 128; idx += 256) {
    int q = idx >> 7, j = idx & 127;
    float2 v = *(const float2*)(qb + q * D_ + 2 * j);
    int phys = (q << 7) | ((((j >> 2) ^ (q & 7)) << 2) | (j & 3));
    qldf[phys] = pack_h2(v.x, v.y);
  }
  // ---- stage ctx tile (raw + w_m-scaled) ----
  const float* cb = ctx + ((size_t)b * C_ + c0) * D_;
  for (int idx = t; idx < CT * 128; idx += 256) {
    int r = idx >> 7, j = idx & 127;
    float2 v = *(const float2*)(cb + r * D_ + 2 * j);
    float2 wm = *(const float2*)(w + 2 * D_ + 2 * j);
    cmld[r][j] = pack_h2(v.x * wm.x, v.y * wm.y);
    crld[r][j] = pack_h2(v.x, v.y);
  }
  if (t < Q_) { qwq_l[t] = qwq_g[b * Q_ + t]; qml[t] = qmask[b * Q_ + t]; }
  if (t < 128) { float2 wc = *(const float2*)(w + 2 * t); wcp[t] = pack_h2(wc.x, wc.y); }
  __syncthreads();

  const int wv = t >> 6, ln = t & 63;
  const int rbase = wv * 4;
  const uint32_t* qrow = qldf + (ln << 7);
  const int swz = ln & 7;

  // ---- sim: lane = q, 4 c-rows per wave sharing question reads ----
  float sv[4];
#pragma unroll
  for (int rr = 0; rr < 4; ++rr) {
    int r = rbase + rr;
    float p = dot2acc(crld[r][ln], wcp[ln], 0.f);
    p = dot2acc(crld[r][64 + ln], wcp[64 + ln], p);
    sv[rr] = wred_sum(p) + qwq_l[ln];   // cwc + qwq
  }
#pragma unroll 2
  for (int j4 = 0; j4 < 32; ++j4) {
    uint4 qp = *(const uint4*)(qrow + ((j4 ^ swz) << 2));
#pragma unroll
    for (int rr = 0; rr < 4; ++rr) {
      uint4 cm = *(const uint4*)(&cmld[rbase + rr][j4 << 2]);
      float s = sv[rr];
      s = dot2acc(qp.x, cm.x, s);
      s = dot2acc(qp.y, cm.y, s);
      s = dot2acc(qp.z, cm.z, s);
      s = dot2acc(qp.w, cm.w, s);
      sv[rr] = s;
    }
  }
  // ---- softmax over q (lane-local values, wave reduces) ----
#pragma unroll
  for (int rr = 0; rr < 4; ++rr) {
    int r = rbase + rr;
    float s = sv[rr];
    float rawmax = wred_max(s);                       // UNMASKED max (reference semantics)
    if (ln == 0) simmax_g[b * C_ + c0 + r] = rawmax;
    float sq = qml[ln] ? s : -FLT_MAX;
    float mm = wred_max(sq);
    float e = __expf(sq - mm);                        // masked lanes -> exp(-huge) = 0
    float se = wred_sum(e);
    ald[r][ln] = e / se;
  }

  // ---- c2q: lane = d-chunk (4 floats), loop q; rows share question reads ----
  float4 acc[4];
#pragma unroll
  for (int rr = 0; rr < 4; ++rr) acc[rr] = float4{0.f, 0.f, 0.f, 0.f};
  const int jc = ln >> 1;
  const int sh = (ln & 1) << 1;
  for (int q = 0; q < Q_; ++q) {
    const uint32_t* qr = qldf + (q << 7) + (((jc ^ (q & 7)) << 2) | sh);
    uint2 qp = *(const uint2*)qr;
    float2 f0 = h2f2(qp.x), f1 = h2f2(qp.y);
#pragma unroll
    for (int rr = 0; rr < 4; ++rr) {
      float av = ald[rbase + rr][q];
      acc[rr].x += av * f0.x; acc[rr].y += av * f0.y;
      acc[rr].z += av * f1.x; acc[rr].w += av * f1.y;
    }
  }
  // ---- write g[0:D]=ctx (exact), g[D:2D]=c2q, g[2D:3D]=ctx*c2q ----
#pragma unroll
  for (int rr = 0; rr < 4; ++rr) {
    int c = c0 + rbase + rr;
    float4 cv = *(const float4*)(ctx + ((size_t)b * C_ + c) * D_ + 4 * ln);
    float* gr = g + ((size_t)b * C_ + c) * (4 * D_);
    *(float4*)(gr + 4 * ln) = cv;
    *(float4*)(gr + D_ + 4 * ln) = acc[rr];
    float4 p2{cv.x * acc[rr].x, cv.y * acc[rr].y, cv.z * acc[rr].z, cv.w * acc[rr].w};
    *(float4*)(gr + 2 * D_ + 4 * ln) = p2;
  }
}

// K3a: per-batch masked softmax over sim_max (C=512) -> bl weights
__global__ __launch_bounds__(256) void k_bsoft(const float* __restrict__ simmax,
                                               const int* __restrict__ cmask,
                                               float* __restrict__ bl) {
  int b = blockIdx.x, t = threadIdx.x;
  int wv = t >> 6, ln = t & 63;
  float v0 = simmax[b * C_ + t], v1 = simmax[b * C_ + 256 + t];
  if (!cmask[b * C_ + t]) v0 = -FLT_MAX;
  if (!cmask[b * C_ + 256 + t]) v1 = -FLT_MAX;
  __shared__ float sred[4];
  __shared__ float ssum[4];
  float mx = wred_max(fmaxf(v0, v1));
  if (ln == 0) sred[wv] = mx;
  __syncthreads();
  float bm = fmaxf(fmaxf(sred[0], sred[1]), fmaxf(sred[2], sred[3]));
  float e0 = __expf(v0 - bm), e1 = __expf(v1 - bm);
  float ps = wred_sum(e0 + e1);
  if (ln == 0) ssum[wv] = ps;
  __syncthreads();
  float bs = ssum[0] + ssum[1] + ssum[2] + ssum[3];
  bl[b * C_ + t] = e0 / bs;
  bl[b * C_ + 256 + t] = e1 / bs;
}

// K3b: partial q2c over 64-row c-chunks (deterministic, no atomics)
__global__ __launch_bounds__(256) void k_q2c_part(const float* __restrict__ ctx,
                                                  const float* __restrict__ bl,
                                                  float* __restrict__ part) {
  int b = blockIdx.x, ch = blockIdx.y, t = threadIdx.x;
  float acc = 0.f;
  int cbeg = ch * 64;
#pragma unroll 4
  for (int c = cbeg; c < cbeg + 64; ++c)
    acc += bl[b * C_ + c] * ctx[((size_t)b * C_ + c) * D_ + t];
  part[((size_t)b * 8 + ch) * D_ + t] = acc;
}

// K3c: reduce partials -> q2c[b, d]
__global__ __launch_bounds__(256) void k_q2c_sum(const float* __restrict__ part,
                                                 float* __restrict__ q2c) {
  int b = blockIdx.x, t = threadIdx.x;
  float s = 0.f;
#pragma unroll
  for (int ch = 0; ch < 8; ++ch) s += part[((size_t)b * 8 + ch) * D_ + t];
  q2c[b * D_ + t] = s;
}

// K4: g[3D:4D] = ctx * q2c (broadcast over c)
__global__ __launch_bounds__(256) void k_g3(const float* __restrict__ ctx,
                                            const float* __restrict__ q2c,
                                            float* __restrict__ g) {
  size_t i = (size_t)blockIdx.x * 256 + threadIdx.x;  // over B*C*64 float4s
  int d4 = (int)(i & 63);
  size_t row = i >> 6;
  int b = (int)(row >> 9);
  float4 cv = *(const float4*)(ctx + row * D_ + 4 * d4);
  float4 qv = *(const float4*)(q2c + (size_t)b * D_ + 4 * d4);
  float4 o{cv.x * qv.x, cv.y * qv.y, cv.z * qv.z, cv.w * qv.w};
  *(float4*)(g + row * (4 * D_) + 3 * D_ + 4 * d4) = o;
}

extern "C" void kernel_launch(void* const* d_in, const int* in_sizes, int n_in,
                              void* d_out, int out_size, void* d_ws, size_t ws_size,
                              hipStream_t stream) {
  const float* ctx   = (const float*)d_in[0];
  const float* qst   = (const float*)d_in[1];
  const int*   cmask = (const int*)d_in[2];
  const int*   qmask = (const int*)d_in[3];
  const float* w     = (const float*)d_in[4];
  float* g  = (float*)d_out;
  float* ws = (float*)d_ws;

  float* qwq    = ws;             // B*Q           = 4096
  float* simmax = ws + 4096;      // B*C           = 32768
  float* bl     = ws + 36864;     // B*C           = 32768
  float* part   = ws + 69632;     // B*8*D         = 131072
  float* q2c    = ws + 200704;    // B*D           = 16384

  k_rowdot<<<dim3(B_ * Q_ / 4), 256, 0, stream>>>(qst, w + D_, qwq, B_ * Q_);
  k_main<<<dim3(C_ / CT, B_), 256, 0, stream>>>(ctx, qst, qmask, w, qwq, g, simmax);
  k_bsoft<<<dim3(B_), 256, 0, stream>>>(simmax, cmask, bl);
  k_q2c_part<<<dim3(B_, 8), 256, 0, stream>>>(ctx, bl, part);
  k_q2c_sum<<<dim3(B_), 256, 0, stream>>>(part, q2c);
  k_g3<<<dim3(B_ * C_ * 64 / 256), 256, 0, stream>>>(ctx, q2c, g);
}

// Round 2
// 99.510 us; speedup vs baseline: 1.1839x; 1.1839x over previous
//
#include <hip/hip_runtime.h>
#include <hip/hip_bf16.h>
#include <float.h>

#define B_ 64
#define C_ 512
#define Q_ 64
#define D_ 256
#define CT 16   // context rows per block in main kernel

typedef _Float16 h2_t __attribute__((ext_vector_type(2)));

union U32H2 { uint32_t u; h2_t h; };

__device__ __forceinline__ uint32_t pack_h2(float a, float b) {
  U32H2 v; v.h = h2_t{(_Float16)a, (_Float16)b}; return v.u;
}
__device__ __forceinline__ h2_t as_h2(uint32_t u) { U32H2 v; v.u = u; return v.h; }

__device__ __forceinline__ float dot2acc(uint32_t q, uint32_t c, float acc) {
#if __has_builtin(__builtin_amdgcn_fdot2)
  return __builtin_amdgcn_fdot2(as_h2(q), as_h2(c), acc, false);
#else
  h2_t ha = as_h2(q), hb = as_h2(c);
  return acc + (float)ha.x * (float)hb.x + (float)ha.y * (float)hb.y;
#endif
}
__device__ __forceinline__ float2 h2f2(uint32_t u) {
  h2_t h = as_h2(u);
  float2 r; r.x = (float)h.x; r.y = (float)h.y; return r;
}

__device__ __forceinline__ float wred_sum(float v) {
#pragma unroll
  for (int off = 32; off > 0; off >>= 1) v += __shfl_xor(v, off, 64);
  return v;
}
__device__ __forceinline__ float wred_max(float v) {
#pragma unroll
  for (int off = 32; off > 0; off >>= 1) v = fmaxf(v, __shfl_xor(v, off, 64));
  return v;
}

// K1: out[row] = dot(src[row, 0:256], wgt[0:256])
__global__ __launch_bounds__(256) void k_rowdot(const float* __restrict__ src,
                                                const float* __restrict__ wgt,
                                                float* __restrict__ out, int nrows) {
  int wv = threadIdx.x >> 6, ln = threadIdx.x & 63;
  int row = blockIdx.x * 4 + wv;
  if (row >= nrows) return;
  float4 s4 = *(const float4*)(src + (size_t)row * D_ + 4 * ln);
  float4 w4 = *(const float4*)(wgt + 4 * ln);
  float p = s4.x * w4.x + s4.y * w4.y + s4.z * w4.z + s4.w * w4.w;
  p = wred_sum(p);
  if (ln == 0) out[row] = p;
}

// K2: per (b, 16-row c-tile): sim -> softmax_q -> c2q; writes g[0:3D], simmax
// LDS = 32768 (qldf) + 8192 (cmld) = 40960 B exactly -> 4 blocks/CU
__global__ __launch_bounds__(256, 4) void k_main(
    const float* __restrict__ ctx, const float* __restrict__ qst,
    const int* __restrict__ qmask, const float* __restrict__ w,
    const float* __restrict__ qwq_g, float* __restrict__ g,
    float* __restrict__ simmax_g) {
  // question[b] as f16 pairs, 16B-chunk XOR-swizzled per row (row=lane reads in sim loop)
  __shared__ __align__(16) uint32_t qldf[Q_ * 128];
  __shared__ __align__(16) uint32_t cmld[CT][128];  // ctx*w_m, f16 pairs (uniform reads)

  const int b = blockIdx.y;
  const int c0 = blockIdx.x * CT;
  const int t = threadIdx.x;
  const int wv = t >> 6, ln = t & 63;
  const int rbase = wv * 4;

  // per-lane weight values (d = 2*ln, 2*ln+1 and d = 128+2*ln, 129+2*ln)
  float2 wc0 = *(const float2*)(w + 2 * ln);
  float2 wc1 = *(const float2*)(w + 128 + 2 * ln);
  float2 wm0 = *(const float2*)(w + 2 * D_ + 2 * ln);
  float2 wm1 = *(const float2*)(w + 2 * D_ + 128 + 2 * ln);

  // ---- stage THIS WAVE's 4 ctx rows (w_m-scaled f16) + fp32 cwc row-dots ----
  const float* cb = ctx + ((size_t)b * C_ + c0) * D_;
  float cwc_r[4];
#pragma unroll
  for (int rr = 0; rr < 4; ++rr) {
    const float* rp = cb + (rbase + rr) * D_;
    float2 v0 = *(const float2*)(rp + 2 * ln);
    float2 v1 = *(const float2*)(rp + 128 + 2 * ln);
    cmld[rbase + rr][ln]      = pack_h2(v0.x * wm0.x, v0.y * wm0.y);
    cmld[rbase + rr][64 + ln] = pack_h2(v1.x * wm1.x, v1.y * wm1.y);
    float p = v0.x * wc0.x + v0.y * wc0.y + v1.x * wc1.x + v1.y * wc1.y;
    cwc_r[rr] = wred_sum(p);  // full row dot, uniform across wave
  }

  // ---- stage question[b] (swizzled), cooperative across block ----
  const float* qb = qst + (size_t)b * Q_ * D_;
  for (int idx = t; idx < Q_ * 128; idx += 256) {
    int q = idx >> 7, j = idx & 127;
    float2 v = *(const float2*)(qb + q * D_ + 2 * j);
    int phys = (q << 7) | ((((j >> 2) ^ (q & 7)) << 2) | (j & 3));
    qldf[phys] = pack_h2(v.x, v.y);
  }
  float qwq_r = qwq_g[b * Q_ + ln];
  int   qml_r = qmask[b * Q_ + ln];
  __syncthreads();

  const uint32_t* qrow = qldf + (ln << 7);
  const int swz = ln & 7;

  // ---- sim: lane = q, 4 c-rows per wave sharing question reads ----
  float sv[4];
#pragma unroll
  for (int rr = 0; rr < 4; ++rr) sv[rr] = cwc_r[rr] + qwq_r;  // cwc + qwq
#pragma unroll 2
  for (int j4 = 0; j4 < 32; ++j4) {
    uint4 qp = *(const uint4*)(qrow + ((j4 ^ swz) << 2));
#pragma unroll
    for (int rr = 0; rr < 4; ++rr) {
      uint4 cm = *(const uint4*)(&cmld[rbase + rr][j4 << 2]);
      float s = sv[rr];
      s = dot2acc(qp.x, cm.x, s);
      s = dot2acc(qp.y, cm.y, s);
      s = dot2acc(qp.z, cm.z, s);
      s = dot2acc(qp.w, cm.w, s);
      sv[rr] = s;
    }
  }
  // ---- softmax over q (lane-local values, wave reduces); a stays in regs ----
  float a_r[4];
#pragma unroll
  for (int rr = 0; rr < 4; ++rr) {
    float s = sv[rr];
    float rawmax = wred_max(s);                       // UNMASKED max (reference semantics)
    if (ln == 0) simmax_g[b * C_ + c0 + rbase + rr] = rawmax;
    float sq = qml_r ? s : -FLT_MAX;
    float mm = wred_max(sq);
    float e = __expf(sq - mm);                        // masked lanes -> exp(-huge) = 0
    float se = wred_sum(e);
    a_r[rr] = e / se;
  }

  // ---- c2q: lane = d-chunk (4 floats), loop q; a broadcast via shfl ----
  float4 acc[4];
#pragma unroll
  for (int rr = 0; rr < 4; ++rr) acc[rr] = float4{0.f, 0.f, 0.f, 0.f};
  const int jc = ln >> 1;
  const int sh = (ln & 1) << 1;
#pragma unroll 4
  for (int q = 0; q < Q_; ++q) {
    const uint32_t* qr = qldf + (q << 7) + (((jc ^ (q & 7)) << 2) | sh);
    uint2 qp = *(const uint2*)qr;
    float2 f0 = h2f2(qp.x), f1 = h2f2(qp.y);
#pragma unroll
    for (int rr = 0; rr < 4; ++rr) {
      float av = __shfl(a_r[rr], q, 64);
      acc[rr].x += av * f0.x; acc[rr].y += av * f0.y;
      acc[rr].z += av * f1.x; acc[rr].w += av * f1.y;
    }
  }
  // ---- write g[0:D]=ctx (exact), g[D:2D]=c2q, g[2D:3D]=ctx*c2q ----
#pragma unroll
  for (int rr = 0; rr < 4; ++rr) {
    int c = c0 + rbase + rr;
    float4 cv = *(const float4*)(ctx + ((size_t)b * C_ + c) * D_ + 4 * ln);
    float* gr = g + ((size_t)b * C_ + c) * (4 * D_);
    *(float4*)(gr + 4 * ln) = cv;
    *(float4*)(gr + D_ + 4 * ln) = acc[rr];
    float4 p2{cv.x * acc[rr].x, cv.y * acc[rr].y, cv.z * acc[rr].z, cv.w * acc[rr].w};
    *(float4*)(gr + 2 * D_ + 4 * ln) = p2;
  }
}

// K3a: per-batch masked softmax over sim_max (C=512) -> bl weights
__global__ __launch_bounds__(256) void k_bsoft(const float* __restrict__ simmax,
                                               const int* __restrict__ cmask,
                                               float* __restrict__ bl) {
  int b = blockIdx.x, t = threadIdx.x;
  int wv = t >> 6, ln = t & 63;
  float v0 = simmax[b * C_ + t], v1 = simmax[b * C_ + 256 + t];
  if (!cmask[b * C_ + t]) v0 = -FLT_MAX;
  if (!cmask[b * C_ + 256 + t]) v1 = -FLT_MAX;
  __shared__ float sred[4];
  __shared__ float ssum[4];
  float mx = wred_max(fmaxf(v0, v1));
  if (ln == 0) sred[wv] = mx;
  __syncthreads();
  float bm = fmaxf(fmaxf(sred[0], sred[1]), fmaxf(sred[2], sred[3]));
  float e0 = __expf(v0 - bm), e1 = __expf(v1 - bm);
  float ps = wred_sum(e0 + e1);
  if (ln == 0) ssum[wv] = ps;
  __syncthreads();
  float bs = ssum[0] + ssum[1] + ssum[2] + ssum[3];
  bl[b * C_ + t] = e0 / bs;
  bl[b * C_ + 256 + t] = e1 / bs;
}

// K3b: partial q2c over 64-row c-chunks (deterministic, no atomics)
__global__ __launch_bounds__(256) void k_q2c_part(const float* __restrict__ ctx,
                                                  const float* __restrict__ bl,
                                                  float* __restrict__ part) {
  int b = blockIdx.x, ch = blockIdx.y, t = threadIdx.x;
  float acc = 0.f;
  int cbeg = ch * 64;
#pragma unroll 4
  for (int c = cbeg; c < cbeg + 64; ++c)
    acc += bl[b * C_ + c] * ctx[((size_t)b * C_ + c) * D_ + t];
  part[((size_t)b * 8 + ch) * D_ + t] = acc;
}

// K3c: reduce partials -> q2c[b, d]
__global__ __launch_bounds__(256) void k_q2c_sum(const float* __restrict__ part,
                                                 float* __restrict__ q2c) {
  int b = blockIdx.x, t = threadIdx.x;
  float s = 0.f;
#pragma unroll
  for (int ch = 0; ch < 8; ++ch) s += part[((size_t)b * 8 + ch) * D_ + t];
  q2c[b * D_ + t] = s;
}

// K4: g[3D:4D] = ctx * q2c (broadcast over c)
__global__ __launch_bounds__(256) void k_g3(const float* __restrict__ ctx,
                                            const float* __restrict__ q2c,
                                            float* __restrict__ g) {
  size_t i = (size_t)blockIdx.x * 256 + threadIdx.x;  // over B*C*64 float4s
  int d4 = (int)(i & 63);
  size_t row = i >> 6;
  int b = (int)(row >> 9);
  float4 cv = *(const float4*)(ctx + row * D_ + 4 * d4);
  float4 qv = *(const float4*)(q2c + (size_t)b * D_ + 4 * d4);
  float4 o{cv.x * qv.x, cv.y * qv.y, cv.z * qv.z, cv.w * qv.w};
  *(float4*)(g + row * (4 * D_) + 3 * D_ + 4 * d4) = o;
}

extern "C" void kernel_launch(void* const* d_in, const int* in_sizes, int n_in,
                              void* d_out, int out_size, void* d_ws, size_t ws_size,
                              hipStream_t stream) {
  const float* ctx   = (const float*)d_in[0];
  const float* qst   = (const float*)d_in[1];
  const int*   cmask = (const int*)d_in[2];
  const int*   qmask = (const int*)d_in[3];
  const float* w     = (const float*)d_in[4];
  float* g  = (float*)d_out;
  float* ws = (float*)d_ws;

  float* qwq    = ws;             // B*Q           = 4096
  float* simmax = ws + 4096;      // B*C           = 32768
  float* bl     = ws + 36864;     // B*C           = 32768
  float* part   = ws + 69632;     // B*8*D         = 131072
  float* q2c    = ws + 200704;    // B*D           = 16384

  k_rowdot<<<dim3(B_ * Q_ / 4), 256, 0, stream>>>(qst, w + D_, qwq, B_ * Q_);
  k_main<<<dim3(C_ / CT, B_), 256, 0, stream>>>(ctx, qst, qmask, w, qwq, g, simmax);
  k_bsoft<<<dim3(B_), 256, 0, stream>>>(simmax, cmask, bl);
  k_q2c_part<<<dim3(B_, 8), 256, 0, stream>>>(ctx, bl, part);
  k_q2c_sum<<<dim3(B_), 256, 0, stream>>>(part, q2c);
  k_g3<<<dim3(B_ * C_ * 64 / 256), 256, 0, stream>>>(ctx, q2c, g);
}

// Round 3
// 66.055 us; speedup vs baseline: 1.7835x; 1.5065x over previous
//
#include <hip/hip_runtime.h>
#include <hip/hip_bf16.h>
#include <float.h>

#define B_ 64
#define C_ 512
#define Q_ 64
#define D_ 256

typedef _Float16 f16x8 __attribute__((ext_vector_type(8)));
typedef float f32x4 __attribute__((ext_vector_type(4)));

union U4H8 { uint4 u; f16x8 h; };
union UH2 { _Float16 h[2]; uint32_t u; };

__device__ __forceinline__ uint32_t packh2(float a, float b) {
  UH2 v; v.h[0] = (_Float16)a; v.h[1] = (_Float16)b; return v.u;
}

__device__ __forceinline__ float wred_sum(float v) {
#pragma unroll
  for (int off = 32; off > 0; off >>= 1) v += __shfl_xor(v, off, 64);
  return v;
}
__device__ __forceinline__ float wred_max(float v) {
#pragma unroll
  for (int off = 32; off > 0; off >>= 1) v = fmaxf(v, __shfl_xor(v, off, 64));
  return v;
}

// K1: out[row] = dot(src[row, 0:256], wgt[0:256])
__global__ __launch_bounds__(256) void k_rowdot(const float* __restrict__ src,
                                                const float* __restrict__ wgt,
                                                float* __restrict__ out, int nrows) {
  int wv = threadIdx.x >> 6, ln = threadIdx.x & 63;
  int row = blockIdx.x * 4 + wv;
  if (row >= nrows) return;
  float4 s4 = *(const float4*)(src + (size_t)row * D_ + 4 * ln);
  float4 w4 = *(const float4*)(wgt + 4 * ln);
  float p = s4.x * w4.x + s4.y * w4.y + s4.z * w4.z + s4.w * w4.w;
  p = wred_sum(p);
  if (ln == 0) out[row] = p;
}

// K2 (MFMA): block = 4 waves, wave = 16 c-rows. simT = mfma(q, ctx*wm),
// softmax over q in C/D layout, P -> LDS bounce -> c2q = mfma(P, qT).
// LDS = 32K(qraw) + 32K(qT) + 8K(P) + .5K = ~74 KB -> 2 blocks/CU.
__global__ __launch_bounds__(256, 2) void k_main(
    const float* __restrict__ ctx, const float* __restrict__ qst,
    const int* __restrict__ qmask, const float* __restrict__ w,
    const float* __restrict__ qwq_g, float* __restrict__ g,
    float* __restrict__ simmax_g) {
  // qraw: [q][k] f16, rows of 256 = 32 chunks(16B); phys chunk low3 ^= (q&7)
  __shared__ __align__(16) ushort qraw[Q_ * D_];
  // qT: [d][q] f16, rows of 64 = 8 chunks(16B); phys chunk ^= (d&7)
  __shared__ __align__(16) ushort qT[D_ * Q_];
  // P per-wave: [c(16)][q(64)] f16, 8 chunks/row; phys chunk ^= (c&7)
  __shared__ __align__(16) ushort pbuf[4][16 * Q_];
  __shared__ float qwq_l[Q_];
  __shared__ int   qml_l[Q_];

  const int bid = blockIdx.x;
  const int b = bid & 63;           // XCD-swizzle: same-b blocks share an XCD
  const int c0 = (bid >> 6) * 64;
  const int t = threadIdx.x;
  const int wv = t >> 6, ln = t & 63;
  const int lc = ln & 15;           // A/B row lane-field, C/D col
  const int lg = ln >> 4;           // k-group
  const int c0w = c0 + wv * 16;

  // ---- B-frags: this wave's 16 ctx rows * w_m (f16), fused g0-copy + fp32 cwc dot ----
  f16x8 bfrag[8];
  float cwc_p = 0.f;
  const float* crow = ctx + ((size_t)b * C_ + c0w + lc) * D_;
  float* grow0 = g + ((size_t)b * C_ + c0w + lc) * (4 * D_);
#pragma unroll
  for (int kk = 0; kk < 8; ++kk) {
    int kb = kk * 32 + lg * 8;
    float4 cv0 = *(const float4*)(crow + kb);
    float4 cv1 = *(const float4*)(crow + kb + 4);
    float4 wc0 = *(const float4*)(w + kb);
    float4 wc1 = *(const float4*)(w + kb + 4);
    float4 wm0 = *(const float4*)(w + 2 * D_ + kb);
    float4 wm1 = *(const float4*)(w + 2 * D_ + kb + 4);
    cwc_p += cv0.x * wc0.x + cv0.y * wc0.y + cv0.z * wc0.z + cv0.w * wc0.w
           + cv1.x * wc1.x + cv1.y * wc1.y + cv1.z * wc1.z + cv1.w * wc1.w;
    bfrag[kk][0] = (_Float16)(cv0.x * wm0.x);
    bfrag[kk][1] = (_Float16)(cv0.y * wm0.y);
    bfrag[kk][2] = (_Float16)(cv0.z * wm0.z);
    bfrag[kk][3] = (_Float16)(cv0.w * wm0.w);
    bfrag[kk][4] = (_Float16)(cv1.x * wm1.x);
    bfrag[kk][5] = (_Float16)(cv1.y * wm1.y);
    bfrag[kk][6] = (_Float16)(cv1.z * wm1.z);
    bfrag[kk][7] = (_Float16)(cv1.w * wm1.w);
    *(float4*)(grow0 + kb) = cv0;          // g[0:D] = ctx exact copy
    *(float4*)(grow0 + kb + 4) = cv1;
  }
  float cwc = cwc_p;
  cwc += __shfl_xor(cwc, 16, 64);
  cwc += __shfl_xor(cwc, 32, 64);          // full row dot for c = c0w+lc

  // ---- stage qraw (coalesced) ----
  const float* qb = qst + (size_t)b * Q_ * D_;
#pragma unroll 4
  for (int it = 0; it < 32; ++it) {
    int idx = it * 256 + t;
    int q = idx >> 7, jp = idx & 127;      // jp = f32-pair index
    float2 v = *(const float2*)(qb + q * D_ + 2 * jp);
    int ch = jp >> 2;
    int phys = (ch & ~7) | ((ch & 7) ^ (q & 7));
    *(uint32_t*)((char*)qraw + q * 512 + phys * 16 + (jp & 3) * 4) = packh2(v.x, v.y);
  }
  // ---- stage qT (transposed; scattered L2-hot reads) ----
#pragma unroll 4
  for (int it = 0; it < 32; ++it) {
    int q = t & 63;
    int jp = (t >> 6) + 4 * it;
    float2 v = *(const float2*)(qb + q * D_ + 2 * jp);
    int d0 = 2 * jp, d1 = d0 + 1;
    UH2 h0; h0.h[0] = (_Float16)v.x;
    UH2 h1; h1.h[0] = (_Float16)v.y;
    *(ushort*)((char*)qT + d0 * 128 + (((q >> 3) ^ (d0 & 7)) << 4) + (q & 7) * 2) = (ushort)(h0.u & 0xffff);
    *(ushort*)((char*)qT + d1 * 128 + (((q >> 3) ^ (d1 & 7)) << 4) + (q & 7) * 2) = (ushort)(h1.u & 0xffff);
  }
  if (t < Q_) { qwq_l[t] = qwq_g[b * Q_ + t]; qml_l[t] = qmask[b * Q_ + t]; }
  __syncthreads();

  // ---- simT[q, c] via MFMA: A = question rows, B = (ctx*wm) cols ----
  f32x4 sacc[4];
#pragma unroll
  for (int tq = 0; tq < 4; ++tq) sacc[tq] = f32x4{0.f, 0.f, 0.f, 0.f};
#pragma unroll
  for (int tq = 0; tq < 4; ++tq) {
    int q = 16 * tq + lc;
#pragma unroll
    for (int kk = 0; kk < 8; ++kk) {
      int ch = lg + 4 * kk;
      int phys = (ch & ~7) | ((ch & 7) ^ (q & 7));
      U4H8 a; a.u = *(const uint4*)((const char*)qraw + q * 512 + phys * 16);
      sacc[tq] = __builtin_amdgcn_mfma_f32_16x16x32_f16(a.h, bfrag[kk], sacc[tq], 0, 0, 0);
    }
  }

  // ---- softmax over q (16 in-lane vals + xor16/xor32), P -> pbuf ----
  float vals[4][4];
  float rmax = -FLT_MAX;
#pragma unroll
  for (int tq = 0; tq < 4; ++tq) {
    float4 qw4 = *(const float4*)(qwq_l + 16 * tq + 4 * lg);
#pragma unroll
    for (int r = 0; r < 4; ++r) {
      float qv = (r == 0) ? qw4.x : (r == 1) ? qw4.y : (r == 2) ? qw4.z : qw4.w;
      vals[tq][r] = sacc[tq][r] + cwc + qv;
      rmax = fmaxf(rmax, vals[tq][r]);
    }
  }
  rmax = fmaxf(rmax, __shfl_xor(rmax, 16, 64));
  rmax = fmaxf(rmax, __shfl_xor(rmax, 32, 64));
  if (ln < 16) simmax_g[b * C_ + c0w + lc] = rmax;   // unmasked max (ref semantics)

  float mmax = -FLT_MAX;
#pragma unroll
  for (int tq = 0; tq < 4; ++tq) {
    int4 qm4 = *(const int4*)(qml_l + 16 * tq + 4 * lg);
#pragma unroll
    for (int r = 0; r < 4; ++r) {
      int m = (r == 0) ? qm4.x : (r == 1) ? qm4.y : (r == 2) ? qm4.z : qm4.w;
      vals[tq][r] = m ? vals[tq][r] : -FLT_MAX;
      mmax = fmaxf(mmax, vals[tq][r]);
    }
  }
  mmax = fmaxf(mmax, __shfl_xor(mmax, 16, 64));
  mmax = fmaxf(mmax, __shfl_xor(mmax, 32, 64));
  float esum = 0.f;
#pragma unroll
  for (int tq = 0; tq < 4; ++tq)
#pragma unroll
    for (int r = 0; r < 4; ++r) {
      vals[tq][r] = __expf(vals[tq][r] - mmax);      // masked -> exp(-huge) = 0
      esum += vals[tq][r];
    }
  esum += __shfl_xor(esum, 16, 64);
  esum += __shfl_xor(esum, 32, 64);
  float inv = 1.f / esum;
#pragma unroll
  for (int tq = 0; tq < 4; ++tq) {
    uint32_t p01 = packh2(vals[tq][0] * inv, vals[tq][1] * inv);
    uint32_t p23 = packh2(vals[tq][2] * inv, vals[tq][3] * inv);
    int qb4 = 16 * tq + 4 * lg;
    int phys = ((qb4 >> 3) ^ (lc & 7));
    char* dst = (char*)pbuf[wv] + lc * 128 + phys * 16 + (qb4 & 7) * 2;
    *(uint2*)dst = uint2{p01, p23};
  }

  // ---- c2q[c, d] via MFMA: A = P rows, B = question^T cols ----
  f16x8 pfrag[2];
#pragma unroll
  for (int ks = 0; ks < 2; ++ks) {
    int phys = (lg + 4 * ks) ^ (lc & 7);
    U4H8 a; a.u = *(const uint4*)((const char*)pbuf[wv] + lc * 128 + phys * 16);
    pfrag[ks] = a.h;
  }
  const float* crow2 = ctx + ((size_t)b * C_ + c0w) * D_;
  float* grow = g + ((size_t)b * C_ + c0w) * (4 * D_);
#pragma unroll 4
  for (int dt = 0; dt < 16; ++dt) {
    int d = dt * 16 + lc;
    f32x4 acc = f32x4{0.f, 0.f, 0.f, 0.f};
#pragma unroll
    for (int ks = 0; ks < 2; ++ks) {
      int phys = (lg + 4 * ks) ^ (d & 7);
      U4H8 bq; bq.u = *(const uint4*)((const char*)qT + d * 128 + phys * 16);
      acc = __builtin_amdgcn_mfma_f32_16x16x32_f16(pfrag[ks], bq.h, acc, 0, 0, 0);
    }
#pragma unroll
    for (int r = 0; r < 4; ++r) {
      int crel = 4 * lg + r;
      float cval = crow2[crel * D_ + d];
      size_t off = (size_t)crel * (4 * D_) + D_ + d;
      grow[off] = acc[r];                 // g[D:2D] = c2q
      grow[off + D_] = cval * acc[r];     // g[2D:3D] = ctx * c2q
    }
  }
}

// K3a: per-batch masked softmax over sim_max (C=512) -> bl weights
__global__ __launch_bounds__(256) void k_bsoft(const float* __restrict__ simmax,
                                               const int* __restrict__ cmask,
                                               float* __restrict__ bl) {
  int b = blockIdx.x, t = threadIdx.x;
  int wv = t >> 6, ln = t & 63;
  float v0 = simmax[b * C_ + t], v1 = simmax[b * C_ + 256 + t];
  if (!cmask[b * C_ + t]) v0 = -FLT_MAX;
  if (!cmask[b * C_ + 256 + t]) v1 = -FLT_MAX;
  __shared__ float sred[4];
  __shared__ float ssum[4];
  float mx = wred_max(fmaxf(v0, v1));
  if (ln == 0) sred[wv] = mx;
  __syncthreads();
  float bm = fmaxf(fmaxf(sred[0], sred[1]), fmaxf(sred[2], sred[3]));
  float e0 = __expf(v0 - bm), e1 = __expf(v1 - bm);
  float ps = wred_sum(e0 + e1);
  if (ln == 0) ssum[wv] = ps;
  __syncthreads();
  float bs = ssum[0] + ssum[1] + ssum[2] + ssum[3];
  bl[b * C_ + t] = e0 / bs;
  bl[b * C_ + 256 + t] = e1 / bs;
}

// K3b: partial q2c over 64-row c-chunks (deterministic, no atomics)
__global__ __launch_bounds__(256) void k_q2c_part(const float* __restrict__ ctx,
                                                  const float* __restrict__ bl,
                                                  float* __restrict__ part) {
  int b = blockIdx.x, ch = blockIdx.y, t = threadIdx.x;
  float acc = 0.f;
  int cbeg = ch * 64;
#pragma unroll 4
  for (int c = cbeg; c < cbeg + 64; ++c)
    acc += bl[b * C_ + c] * ctx[((size_t)b * C_ + c) * D_ + t];
  part[((size_t)b * 8 + ch) * D_ + t] = acc;
}

// K3c: reduce partials -> q2c[b, d]
__global__ __launch_bounds__(256) void k_q2c_sum(const float* __restrict__ part,
                                                 float* __restrict__ q2c) {
  int b = blockIdx.x, t = threadIdx.x;
  float s = 0.f;
#pragma unroll
  for (int ch = 0; ch < 8; ++ch) s += part[((size_t)b * 8 + ch) * D_ + t];
  q2c[b * D_ + t] = s;
}

// K4: g[3D:4D] = ctx * q2c (broadcast over c)
__global__ __launch_bounds__(256) void k_g3(const float* __restrict__ ctx,
                                            const float* __restrict__ q2c,
                                            float* __restrict__ g) {
  size_t i = (size_t)blockIdx.x * 256 + threadIdx.x;  // over B*C*64 float4s
  int d4 = (int)(i & 63);
  size_t row = i >> 6;
  int b = (int)(row >> 9);
  float4 cv = *(const float4*)(ctx + row * D_ + 4 * d4);
  float4 qv = *(const float4*)(q2c + (size_t)b * D_ + 4 * d4);
  float4 o{cv.x * qv.x, cv.y * qv.y, cv.z * qv.z, cv.w * qv.w};
  *(float4*)(g + row * (4 * D_) + 3 * D_ + 4 * d4) = o;
}

extern "C" void kernel_launch(void* const* d_in, const int* in_sizes, int n_in,
                              void* d_out, int out_size, void* d_ws, size_t ws_size,
                              hipStream_t stream) {
  const float* ctx   = (const float*)d_in[0];
  const float* qst   = (const float*)d_in[1];
  const int*   cmask = (const int*)d_in[2];
  const int*   qmask = (const int*)d_in[3];
  const float* w     = (const float*)d_in[4];
  float* g  = (float*)d_out;
  float* ws = (float*)d_ws;

  float* qwq    = ws;             // B*Q           = 4096
  float* simmax = ws + 4096;      // B*C           = 32768
  float* bl     = ws + 36864;     // B*C           = 32768
  float* part   = ws + 69632;     // B*8*D         = 131072
  float* q2c    = ws + 200704;    // B*D           = 16384

  k_rowdot<<<dim3(B_ * Q_ / 4), 256, 0, stream>>>(qst, w + D_, qwq, B_ * Q_);
  k_main<<<dim3(512), 256, 0, stream>>>(ctx, qst, qmask, w, qwq, g, simmax);
  k_bsoft<<<dim3(B_), 256, 0, stream>>>(simmax, cmask, bl);
  k_q2c_part<<<dim3(B_, 8), 256, 0, stream>>>(ctx, bl, part);
  k_q2c_sum<<<dim3(B_), 256, 0, stream>>>(part, q2c);
  k_g3<<<dim3(B_ * C_ * 64 / 256), 256, 0, stream>>>(ctx, q2c, g);
}